// Round 4
// baseline (321.658 us; speedup 1.0000x reference)
//
#include <hip/hip_runtime.h>
#include <hip/hip_bf16.h>
#include <stdint.h>

typedef unsigned int u32;
typedef unsigned short u16;
typedef unsigned char u8;
typedef __bf16 bf16x8 __attribute__((ext_vector_type(8)));
typedef float f32x4 __attribute__((ext_vector_type(4)));

#define NB 65536
#define NBLK 1280                    // 256 buckets padded to 64 rows: max 81664 rows
#define PERM_TOT (NBLK * 64)
#define INVR 0xFFFFFFFFu
#define BLK_DEAD 0xFFFFu

// LDS layout (bytes) — dieted to 54,272 B so 3 blocks/CU fit (3*(54272+256) <= 160 KiB)
#define O_ROWS 0
#define O_XJ   256
#define SR_XJ  64                    // 32 bf16, no pad (2-way conflict = free)
#define O_P    (256 + 64 * SR_XJ)    // 4352
#define SR_P   260                   // (128+2) bf16, 1-bank shift/row
#define O_H    (O_P + 64 * SR_P)     // 20992
#define SR_H   520                   // (256+4) bf16, 2-bank shift/row
#define O_RED  O_P                   // node3 partials alias P (16384 <= 16640)
#define SM_BYTES (O_H + 64 * SR_H)   // 54272

// packed-weight tile starts (512 elems = 1KB per 32x16 tile)
// order: W0_0, W0_1, W1_pre, W1_0, W1_1, W2_pre, W2_0, W2_1, W3_pre, W3_0, W3_1
__device__ __host__ constexpr int TS(int m) {
  constexpr int t[12] = {0, 64, 320, 384, 1152, 1408, 1472, 2240, 2496, 2560, 3328, 3360};
  return t[m];
}

__device__ __forceinline__ u16 f2bf(float f) {
  u32 u = __builtin_bit_cast(u32, f);
  u32 r = (u + 0x7FFFu + ((u >> 16) & 1u)) >> 16;   // RNE
  return (u16)r;
}
__device__ __forceinline__ float relu_f(float x) { return x > 0.f ? x : 0.f; }
__device__ __forceinline__ f32x4 mfma16(bf16x8 a, bf16x8 b, f32x4 c) {
  return __builtin_amdgcn_mfma_f32_16x16x32_bf16(a, b, c, 0, 0, 0);
}

// Pack 4 accumulator values (rows quad*4+0..3, col l16 of 16x16 D tile) into two
// bf16-pair words via neighbor-lane exchange (verified round 1/3).
__device__ __forceinline__ void mkpair(f32x4 acc, float bias, bool dorelu, int l16,
                                       u32& w0, u32& w1) {
  float v0 = acc[0] + bias, v1 = acc[1] + bias, v2 = acc[2] + bias, v3 = acc[3] + bias;
  if (dorelu) { v0 = relu_f(v0); v1 = relu_f(v1); v2 = relu_f(v2); v3 = relu_f(v3); }
  u32 a = (u32)f2bf(v0) | ((u32)f2bf(v1) << 16);
  u32 b = (u32)f2bf(v2) | ((u32)f2bf(v3) << 16);
  u32 ax = (u32)__shfl_xor((int)a, 1);
  u32 bx = (u32)__shfl_xor((int)b, 1);
  if ((l16 & 1) == 0) { w0 = (a & 0xffffu) | (ax << 16); w1 = (a >> 16) | (ax & 0xffff0000u); }
  else                { w0 = (bx & 0xffffu) | (b << 16); w1 = (bx >> 16) | (b & 0xffff0000u); }
}

// ---------------- routing (256 tuple-buckets) ----------------

__global__ void k_init(u32* cnt) { cnt[threadIdx.x] = 0u; }   // 256 thr

__global__ void k_route(const float* __restrict__ inp, u8* __restrict__ bkt,
                        u32* __restrict__ cnt) {
  __shared__ u32 h[256];
  const int tid = threadIdx.x;
  h[tid] = 0u;
  __syncthreads();
  const int r = blockIdx.x * 256 + tid;
  const float4* oh = (const float4*)(inp + (size_t)r * 144 + 128);
  u32 b = 0;
#pragma unroll
  for (int j = 0; j < 4; j++) {
    float4 v = oh[j];
    u32 e = v.y > 0.5f ? 1u : (v.z > 0.5f ? 2u : (v.w > 0.5f ? 3u : 0u));
    b |= e << (2 * j);
  }
  bkt[r] = (u8)b;
  atomicAdd(&h[b], 1u);
  __syncthreads();
  atomicAdd(&cnt[tid], h[tid]);
}

__global__ void k_scan(const u32* __restrict__ cnt, u32* __restrict__ cur,
                       u16* __restrict__ blk2b, u32* __restrict__ perm) {
  __shared__ u32 s[256];
  const int tid = threadIdx.x;
  const u32 c = cnt[tid];
  const u32 pad = (c + 63u) & ~63u;
  s[tid] = pad;
  __syncthreads();
  for (int d = 1; d < 256; d <<= 1) {
    u32 v = (tid >= d) ? s[tid - d] : 0u;
    __syncthreads();
    s[tid] += v;
    __syncthreads();
  }
  const u32 off = s[tid] - pad;        // exclusive padded offset
  const u32 total = s[255];
  cur[tid] = off;
  for (u32 i = off + c; i < off + pad; i++) perm[i] = INVR;
  // u16 blk2b: bucket 255 is a REAL bucket, 0xFFFF is the dead sentinel
  for (u32 blk = off >> 6; blk < (off + pad) >> 6; blk++) blk2b[blk] = (u16)tid;
  for (u32 i = total + tid; i < PERM_TOT; i += 256) perm[i] = INVR;
  for (u32 blk = (total >> 6) + tid; blk < NBLK; blk += 256) blk2b[blk] = BLK_DEAD;
}

__global__ void k_scatter(const u8* __restrict__ bkt, u32* __restrict__ cur,
                          u32* __restrict__ perm) {
  __shared__ u32 h[256], base[256];
  const int tid = threadIdx.x;
  h[tid] = 0u;
  __syncthreads();
  const int r = blockIdx.x * 256 + tid;
  const u32 b = bkt[r];
  const u32 rank = atomicAdd(&h[b], 1u);
  __syncthreads();
  base[tid] = h[tid] ? atomicAdd(&cur[tid], h[tid]) : 0u;
  __syncthreads();
  perm[base[b] + rank] = (u32)r;
}

// ---------------- weight packing ----------------
// Tile (kt,nt): lane L holds B[kt*32 + (L>>4)*8 + j][nt*16 + (L&15)], j=0..7.
// Tile order [e][nt][kt].

struct PrepArgs {
  const float* src[11];
  int K[11], Nsrc[11];
  int tileStart[12];
};

__global__ void k_prep(__bf16* __restrict__ pk, PrepArgs pa) {
  const int tid = threadIdx.x;
  const int gt = blockIdx.x * 4 + (tid >> 6);
  const int lane = tid & 63, quad = lane >> 4, l16 = lane & 15;
  int m = 0;
  while (gt >= pa.tileStart[m + 1]) m++;
  const int loc = gt - pa.tileStart[m];
  const int K = pa.K[m], Ns = pa.Nsrc[m];
  const int Np = Ns < 16 ? 16 : Ns;
  const int KT = K >> 5, NT = Np >> 4;
  const int e = loc / (KT * NT), rem = loc % (KT * NT);
  const int nt = rem / KT, kt = rem % KT;
  const int k = kt * 32 + quad * 8, n = nt * 16 + l16;
  u32 hw[4];
  if (n < Ns) {
    const float* s = pa.src[m] + ((size_t)e * K + k) * Ns + n;
    u16 h[8];
#pragma unroll
    for (int j = 0; j < 8; j++) h[j] = f2bf(s[(size_t)j * Ns]);
    hw[0] = (u32)h[0] | ((u32)h[1] << 16);
    hw[1] = (u32)h[2] | ((u32)h[3] << 16);
    hw[2] = (u32)h[4] | ((u32)h[5] << 16);
    hw[3] = (u32)h[6] | ((u32)h[7] << 16);
  } else {
    hw[0] = hw[1] = hw[2] = hw[3] = 0u;
  }
  uint4 w; w.x = hw[0]; w.y = hw[1]; w.z = hw[2]; w.w = hw[3];
  *(uint4*)((char*)pk + (size_t)gt * 1024 + lane * 16) = w;
}

// ---------------- fused node-chain kernel ----------------

__device__ __forceinline__ void xj_load(const float* inp, u32 myrow, int tid, int node,
                                        float4& v0, float4& v1) {
  v0 = make_float4(0.f, 0.f, 0.f, 0.f); v1 = v0;
  if (myrow != INVR) {
    const int c8 = (tid & 3) << 3;
    const float4* p = (const float4*)(inp + (size_t)myrow * 144 + node * 32 + c8);
    v0 = p[0]; v1 = p[1];
  }
}

__device__ __forceinline__ void xj_store(char* sm, int tid, float4 v0, float4 v1) {
  const int r = tid >> 2, c8 = (tid & 3) << 3;
  uint4 w;
  w.x = (u32)f2bf(v0.x) | ((u32)f2bf(v0.y) << 16);
  w.y = (u32)f2bf(v0.z) | ((u32)f2bf(v0.w) << 16);
  w.z = (u32)f2bf(v1.x) | ((u32)f2bf(v1.y) << 16);
  w.w = (u32)f2bf(v1.z) | ((u32)f2bf(v1.w) << 16);
  *(uint4*)(sm + O_XJ + r * SR_XJ + c8 * 2) = w;
}

// h = relu(xj @ Wp + bp) -> H  (also node0's first GEMM)
__device__ __forceinline__ void pre_gemm(char* sm, u32 e, int wave, int lane,
                                         const __bf16* Wp, const float* bp) {
  const int quad = lane >> 4, l16 = lane & 15;
  const int wn0 = wave * 64;
  const int rsel = quad * 4 + ((l16 & 1) ? 2 : 0);
  const int colp = l16 & ~1;
  float bias[4];
#pragma unroll
  for (int nt = 0; nt < 4; nt++) bias[nt] = bp[(size_t)e * 256 + wn0 + nt * 16 + l16];
  f32x4 acc[4][4];
#pragma unroll
  for (int i = 0; i < 4; i++)
#pragma unroll
    for (int j = 0; j < 4; j++) acc[i][j] = (f32x4){0.f, 0.f, 0.f, 0.f};
  bf16x8 a[4], b[4];
#pragma unroll
  for (int nt = 0; nt < 4; nt++)
    b[nt] = *(const bf16x8*)(Wp + (size_t)(e * 16 + (wn0 >> 4) + nt) * 512 + lane * 8);
#pragma unroll
  for (int mt = 0; mt < 4; mt++)
    a[mt] = *(const bf16x8*)(sm + O_XJ + (mt * 16 + l16) * SR_XJ + quad * 16);
#pragma unroll
  for (int mt = 0; mt < 4; mt++)
#pragma unroll
    for (int nt = 0; nt < 4; nt++) acc[mt][nt] = mfma16(a[mt], b[nt], acc[mt][nt]);
#pragma unroll
  for (int nt = 0; nt < 4; nt++) {
    const int n = wn0 + nt * 16;
#pragma unroll
    for (int mt = 0; mt < 4; mt++) {
      u32 w0, w1;
      mkpair(acc[mt][nt], bias[nt], true, l16, w0, w1);
      char* d = sm + O_H + (mt * 16 + rsel) * SR_H + (n + colp) * 2;
      *(u32*)d = w0; *(u32*)(d + SR_H) = w1;
    }
  }
}

// h = relu(cat(P, H) @ Wm + bm) -> H   (K=384; kt 0..3 from P, 4..11 from H)
__device__ __forceinline__ void main_gemm(char* sm, u32 e, int wave, int lane,
                                          const __bf16* Wm, const float* bm) {
  const int quad = lane >> 4, l16 = lane & 15;
  const int wn0 = wave * 64;
  const int rsel = quad * 4 + ((l16 & 1) ? 2 : 0);
  const int colp = l16 & ~1;
  float bias[4];
#pragma unroll
  for (int nt = 0; nt < 4; nt++) bias[nt] = bm[(size_t)e * 256 + wn0 + nt * 16 + l16];
  f32x4 acc[4][4];
#pragma unroll
  for (int i = 0; i < 4; i++)
#pragma unroll
    for (int j = 0; j < 4; j++) acc[i][j] = (f32x4){0.f, 0.f, 0.f, 0.f};
  const __bf16* bB = Wm + (size_t)(e * 16 + (wn0 >> 4)) * 12 * 512 + lane * 8;
  bf16x8 bb[2][4];
#pragma unroll
  for (int nt = 0; nt < 4; nt++) {
    bb[0][nt] = *(const bf16x8*)(bB + (size_t)(nt * 12 + 0) * 512);
    bb[1][nt] = *(const bf16x8*)(bB + (size_t)(nt * 12 + 1) * 512);
  }
#pragma unroll
  for (int kt = 0; kt < 12; kt++) {
    bf16x8 a[4];
#pragma unroll
    for (int mt = 0; mt < 4; mt++) {
      a[mt] = (kt < 4)
          ? *(const bf16x8*)(sm + O_P + (mt * 16 + l16) * SR_P + kt * 64 + quad * 16)
          : *(const bf16x8*)(sm + O_H + (mt * 16 + l16) * SR_H + (kt - 4) * 64 + quad * 16);
    }
#pragma unroll
    for (int mt = 0; mt < 4; mt++)
#pragma unroll
      for (int nt = 0; nt < 4; nt++) acc[mt][nt] = mfma16(a[mt], bb[kt & 1][nt], acc[mt][nt]);
    if (kt < 10) {
#pragma unroll
      for (int nt = 0; nt < 4; nt++)
        bb[kt & 1][nt] = *(const bf16x8*)(bB + (size_t)(nt * 12 + kt + 2) * 512);
    }
  }
  __syncthreads();   // all waves done reading P/H before H is overwritten
#pragma unroll
  for (int nt = 0; nt < 4; nt++) {
    const int n = wn0 + nt * 16;
#pragma unroll
    for (int mt = 0; mt < 4; mt++) {
      u32 w0, w1;
      mkpair(acc[mt][nt], bias[nt], true, l16, w0, w1);
      char* d = sm + O_H + (mt * 16 + rsel) * SR_H + (n + colp) * 2;
      *(u32*)d = w0; *(u32*)(d + SR_H) = w1;
    }
  }
  __syncthreads();
}

// xnext = relu(H @ Wo + bo) -> P  (nodes 0..2)
__device__ __forceinline__ void out_gemm(char* sm, u32 e, int wave, int lane,
                                         const __bf16* Wo, const float* bo) {
  const int quad = lane >> 4, l16 = lane & 15;
  const int on0 = wave * 32;
  const int rsel = quad * 4 + ((l16 & 1) ? 2 : 0);
  const int colp = l16 & ~1;
  float bias[2];
#pragma unroll
  for (int nt = 0; nt < 2; nt++) bias[nt] = bo[(size_t)e * 128 + on0 + nt * 16 + l16];
  f32x4 acc[4][2];
#pragma unroll
  for (int i = 0; i < 4; i++) { acc[i][0] = (f32x4){0.f,0.f,0.f,0.f}; acc[i][1] = acc[i][0]; }
  const __bf16* bB = Wo + (size_t)(e * 8 + (on0 >> 4)) * 8 * 512 + lane * 8;
  bf16x8 bb[2][2];
#pragma unroll
  for (int nt = 0; nt < 2; nt++) {
    bb[0][nt] = *(const bf16x8*)(bB + (size_t)(nt * 8 + 0) * 512);
    bb[1][nt] = *(const bf16x8*)(bB + (size_t)(nt * 8 + 1) * 512);
  }
#pragma unroll
  for (int kt = 0; kt < 8; kt++) {
    bf16x8 a[4];
#pragma unroll
    for (int mt = 0; mt < 4; mt++)
      a[mt] = *(const bf16x8*)(sm + O_H + (mt * 16 + l16) * SR_H + kt * 64 + quad * 16);
#pragma unroll
    for (int mt = 0; mt < 4; mt++)
#pragma unroll
      for (int nt = 0; nt < 2; nt++) acc[mt][nt] = mfma16(a[mt], bb[kt & 1][nt], acc[mt][nt]);
    if (kt < 6) {
#pragma unroll
      for (int nt = 0; nt < 2; nt++)
        bb[kt & 1][nt] = *(const bf16x8*)(bB + (size_t)(nt * 8 + kt + 2) * 512);
    }
  }
#pragma unroll
  for (int nt = 0; nt < 2; nt++) {
    const int n = on0 + nt * 16;
#pragma unroll
    for (int mt = 0; mt < 4; mt++) {
      u32 w0, w1;
      mkpair(acc[mt][nt], bias[nt], true, l16, w0, w1);
      char* d = sm + O_P + (mt * 16 + rsel) * SR_P + (n + colp) * 2;
      *(u32*)d = w0; *(u32*)(d + SR_P) = w1;
    }
  }
}

__global__ __launch_bounds__(256, 3) void fused_k(
    const float* __restrict__ inp, const u32* __restrict__ perm,
    const u16* __restrict__ blk2b, const __bf16* __restrict__ pk,
    const float* __restrict__ b0_0, const float* __restrict__ b0_1,
    const float* __restrict__ b1_p, const float* __restrict__ b1_0,
    const float* __restrict__ b1_1, const float* __restrict__ b2_p,
    const float* __restrict__ b2_0, const float* __restrict__ b2_1,
    const float* __restrict__ b3_p, const float* __restrict__ b3_0,
    const float* __restrict__ b3_1, float* __restrict__ dout) {
  const u32 b = blk2b[blockIdx.x];
  if (b == BLK_DEAD) return;
  __shared__ __align__(16) char sm[SM_BYTES];
  u32* rows = (u32*)sm;
  const int tid = threadIdx.x;
  const int wave = tid >> 6, lane = tid & 63, quad = lane >> 4, l16 = lane & 15;
  if (tid < 64) rows[tid] = perm[blockIdx.x * 64 + tid];
  const u32 e0 = b & 3u, e1 = (b >> 2) & 3u, e2 = (b >> 4) & 3u, e3 = (b >> 6) & 3u;
  __syncthreads();
  const u32 myrow = rows[tid >> 2];

  float4 v0, v1;
  // ---- node 0 ----
  xj_load(inp, myrow, tid, 0, v0, v1);
  xj_store(sm, tid, v0, v1);
  __syncthreads();
  pre_gemm(sm, e0, wave, lane, pk + (size_t)TS(0) * 512, b0_0);   // h0 -> H
  __syncthreads();
  // ---- node 1 ----
  xj_load(inp, myrow, tid, 1, v0, v1);
  out_gemm(sm, e0, wave, lane, pk + (size_t)TS(1) * 512, b0_1);   // x -> P
  xj_store(sm, tid, v0, v1);
  __syncthreads();
  pre_gemm(sm, e1, wave, lane, pk + (size_t)TS(2) * 512, b1_p);
  __syncthreads();
  main_gemm(sm, e1, wave, lane, pk + (size_t)TS(3) * 512, b1_0);
  // ---- node 2 ----
  xj_load(inp, myrow, tid, 2, v0, v1);
  out_gemm(sm, e1, wave, lane, pk + (size_t)TS(4) * 512, b1_1);
  xj_store(sm, tid, v0, v1);
  __syncthreads();
  pre_gemm(sm, e2, wave, lane, pk + (size_t)TS(5) * 512, b2_p);
  __syncthreads();
  main_gemm(sm, e2, wave, lane, pk + (size_t)TS(6) * 512, b2_0);
  // ---- node 3 ----
  xj_load(inp, myrow, tid, 3, v0, v1);
  out_gemm(sm, e2, wave, lane, pk + (size_t)TS(7) * 512, b2_1);
  xj_store(sm, tid, v0, v1);
  __syncthreads();
  pre_gemm(sm, e3, wave, lane, pk + (size_t)TS(8) * 512, b3_p);
  __syncthreads();
  main_gemm(sm, e3, wave, lane, pk + (size_t)TS(9) * 512, b3_0);

  // out3: [64x256] @ W3_1[256x16pad] + b -> dout fp32 (K split across waves)
  {
    const __bf16* Wo3 = pk + (size_t)TS(10) * 512;
    f32x4 acc3[4];
#pragma unroll
    for (int i = 0; i < 4; i++) acc3[i] = (f32x4){0.f, 0.f, 0.f, 0.f};
#pragma unroll
    for (int kk = 0; kk < 2; kk++) {
      const int kt = wave * 2 + kk;
      bf16x8 b3 = *(const bf16x8*)(Wo3 + (size_t)(e3 * 8 + kt) * 512 + lane * 8);
      bf16x8 a[4];
#pragma unroll
      for (int mt = 0; mt < 4; mt++)
        a[mt] = *(const bf16x8*)(sm + O_H + (mt * 16 + l16) * SR_H + kt * 64 + quad * 16);
#pragma unroll
      for (int mt = 0; mt < 4; mt++) acc3[mt] = mfma16(a[mt], b3, acc3[mt]);
    }
#pragma unroll
    for (int mt = 0; mt < 4; mt++)
#pragma unroll
      for (int r = 0; r < 4; r++)
        *(float*)(sm + O_RED +
                  (((size_t)wave * 64 + mt * 16 + quad * 4 + r) * 16 + l16) * 4) = acc3[mt][r];
    __syncthreads();
    const int m = tid >> 2, c = (tid & 3) * 2;
    float s0 = 0.f, s1 = 0.f;
#pragma unroll
    for (int w = 0; w < 4; w++) {
      s0 += *(float*)(sm + O_RED + (((size_t)w * 64 + m) * 16 + c) * 4);
      s1 += *(float*)(sm + O_RED + (((size_t)w * 64 + m) * 16 + c + 1) * 4);
    }
    if (myrow != INVR) {
      float2 o;
      o.x = s0 + b3_1[(size_t)e3 * 8 + c];
      o.y = s1 + b3_1[(size_t)e3 * 8 + c + 1];
      *(float2*)(dout + (size_t)myrow * 8 + c) = o;
    }
  }
}

// ---------------- host ----------------

extern "C" void kernel_launch(void* const* d_in, const int* in_sizes, int n_in,
                              void* d_out, int out_size, void* d_ws, size_t ws_size,
                              hipStream_t stream) {
  (void)in_sizes; (void)n_in; (void)out_size; (void)ws_size;
  const float* inp = (const float*)d_in[0];
  char* ws = (char*)d_ws;

  const size_t oCNT = 0;                       // 256 u32
  const size_t oCUR = 1024;                    // 256 u32
  const size_t oBKT = 2048;                    // NB u8
  const size_t oB2B = oBKT + NB;               // NBLK u16
  const size_t oPERM = (oB2B + NBLK * 2 + 255) & ~(size_t)255;
  const size_t oPK = (oPERM + (size_t)PERM_TOT * 4 + 255) & ~(size_t)255;

  u32* cnt = (u32*)(ws + oCNT);
  u32* cur = (u32*)(ws + oCUR);
  u8* bkt = (u8*)(ws + oBKT);
  u16* blk2b = (u16*)(ws + oB2B);
  u32* perm = (u32*)(ws + oPERM);
  __bf16* pk = (__bf16*)(ws + oPK);

  PrepArgs pa;
  const int widx[11] = {1, 3, 5, 7, 9, 11, 13, 15, 17, 19, 21};
  const int Ks[11] = {32, 256, 32, 384, 256, 32, 384, 256, 32, 384, 256};
  const int Ns[11] = {256, 128, 256, 256, 128, 256, 256, 128, 256, 256, 8};
  for (int m = 0; m < 11; m++) {
    pa.src[m] = (const float*)d_in[widx[m]];
    pa.K[m] = Ks[m]; pa.Nsrc[m] = Ns[m]; pa.tileStart[m] = TS(m);
  }
  pa.tileStart[11] = TS(11);   // 3360 tiles

  hipLaunchKernelGGL(k_init, dim3(1), dim3(256), 0, stream, cnt);
  hipLaunchKernelGGL(k_prep, dim3(TS(11) / 4), dim3(256), 0, stream, pk, pa);
  hipLaunchKernelGGL(k_route, dim3(NB / 256), dim3(256), 0, stream, inp, bkt, cnt);
  hipLaunchKernelGGL(k_scan, dim3(1), dim3(256), 0, stream, cnt, cur, blk2b, perm);
  hipLaunchKernelGGL(k_scatter, dim3(NB / 256), dim3(256), 0, stream, bkt, cur, perm);

  fused_k<<<NBLK, 256, 0, stream>>>(
      inp, perm, blk2b, pk,
      (const float*)d_in[2], (const float*)d_in[4],
      (const float*)d_in[6], (const float*)d_in[8], (const float*)d_in[10],
      (const float*)d_in[12], (const float*)d_in[14], (const float*)d_in[16],
      (const float*)d_in[18], (const float*)d_in[20], (const float*)d_in[22],
      (float*)d_out);
}

// Round 5
// 229.514 us; speedup vs baseline: 1.4015x; 1.4015x over previous
//
#include <hip/hip_runtime.h>
#include <hip/hip_bf16.h>
#include <stdint.h>

typedef unsigned int u32;
typedef unsigned short u16;
typedef unsigned char u8;
typedef __bf16 bf16x8 __attribute__((ext_vector_type(8)));
typedef float f32x4 __attribute__((ext_vector_type(4)));

#define NB 65536
#define NBLK 1280                    // 256 buckets padded to 64 rows: max 81664 rows
#define PERM_TOT (NBLK * 64)
#define INVR 0xFFFFFFFFu
#define BLK_DEAD 0xFFFFu

// LDS layout (bytes) — activations in MFMA A-fragment tile layout:
// region[mt][kt] 16x32 tile = 1KB, addr = (mt*KT+kt)*1024 + lane*16.
// All inner-loop ds_read_b128 are conflict-free and 16B-aligned.
#define O_ROWS 0
#define O_XJ   256                   // 4 tiles  (KT=1)  = 4 KB
#define O_P    (O_XJ + 4096)         // 16 tiles (KT=4)  = 16 KB
#define O_H    (O_P + 16384)         // 32 tiles (KT=8)  = 32 KB
#define O_RED  O_P                   // node3 partials alias P (16 KB exactly)
#define SM_BYTES (O_H + 32768)       // 53,504 -> 3 blocks/CU

// packed-weight tile starts (512 elems = 1KB per 32x16 tile)
// order: W0_0, W0_1, W1_pre, W1_0, W1_1, W2_pre, W2_0, W2_1, W3_pre, W3_0, W3_1
__device__ __host__ constexpr int TS(int m) {
  constexpr int t[12] = {0, 64, 320, 384, 1152, 1408, 1472, 2240, 2496, 2560, 3328, 3360};
  return t[m];
}

__device__ __forceinline__ u16 f2bf(float f) {
  u32 u = __builtin_bit_cast(u32, f);
  u32 r = (u + 0x7FFFu + ((u >> 16) & 1u)) >> 16;   // RNE
  return (u16)r;
}
__device__ __forceinline__ float relu_f(float x) { return x > 0.f ? x : 0.f; }
__device__ __forceinline__ f32x4 mfma16(bf16x8 a, bf16x8 b, f32x4 c) {
  return __builtin_amdgcn_mfma_f32_16x16x32_bf16(a, b, c, 0, 0, 0);
}

// Pack 4 accumulator values (rows quad*4+0..3, col l16 of 16x16 D tile) into two
// bf16-pair words via neighbor-lane exchange (verified rounds 1/3).
// w0 = (row m0, cols col,col+1), w1 = (row m0+1, cols col,col+1), col even.
__device__ __forceinline__ void mkpair(f32x4 acc, float bias, bool dorelu, int l16,
                                       u32& w0, u32& w1) {
  float v0 = acc[0] + bias, v1 = acc[1] + bias, v2 = acc[2] + bias, v3 = acc[3] + bias;
  if (dorelu) { v0 = relu_f(v0); v1 = relu_f(v1); v2 = relu_f(v2); v3 = relu_f(v3); }
  u32 a = (u32)f2bf(v0) | ((u32)f2bf(v1) << 16);
  u32 b = (u32)f2bf(v2) | ((u32)f2bf(v3) << 16);
  u32 ax = (u32)__shfl_xor((int)a, 1);
  u32 bx = (u32)__shfl_xor((int)b, 1);
  if ((l16 & 1) == 0) { w0 = (a & 0xffffu) | (ax << 16); w1 = (a >> 16) | (ax & 0xffff0000u); }
  else                { w0 = (bx & 0xffffu) | (b << 16); w1 = (bx >> 16) | (b & 0xffff0000u); }
}

// Store the (m0,col)/(m0+1,col) u32 pair into a fragment-layout region.
// element (row,col) -> tile(row>>4, col>>5), slot (row&15) + 16*((col&31)>>3),
// byte (col&7)*2. Row m0+1 (m0&15 <= 14) = slot+1 = +16 bytes.
__device__ __forceinline__ void frag_store_pair(char* base, int KT, int m0, int col,
                                                u32 w0, u32 w1) {
  char* d = base + (((m0 >> 4) * KT + (col >> 5)) << 10) +
            (((m0 & 15) + (((col & 31) >> 3) << 4)) << 4) + (col & 7) * 2;
  *(u32*)d = w0; *(u32*)(d + 16) = w1;
}

// ---------------- routing (256 tuple-buckets) ----------------

__global__ void k_init(u32* cnt) { cnt[threadIdx.x] = 0u; }   // 256 thr

__global__ void k_route(const float* __restrict__ inp, u8* __restrict__ bkt,
                        u32* __restrict__ cnt) {
  __shared__ u32 h[256];
  const int tid = threadIdx.x;
  h[tid] = 0u;
  __syncthreads();
  const int r = blockIdx.x * 256 + tid;
  const float4* oh = (const float4*)(inp + (size_t)r * 144 + 128);
  u32 b = 0;
#pragma unroll
  for (int j = 0; j < 4; j++) {
    float4 v = oh[j];
    u32 e = v.y > 0.5f ? 1u : (v.z > 0.5f ? 2u : (v.w > 0.5f ? 3u : 0u));
    b |= e << (2 * j);
  }
  bkt[r] = (u8)b;
  atomicAdd(&h[b], 1u);
  __syncthreads();
  atomicAdd(&cnt[tid], h[tid]);
}

__global__ void k_scan(const u32* __restrict__ cnt, u32* __restrict__ cur,
                       u16* __restrict__ blk2b, u32* __restrict__ perm) {
  __shared__ u32 s[256];
  const int tid = threadIdx.x;
  const u32 c = cnt[tid];
  const u32 pad = (c + 63u) & ~63u;
  s[tid] = pad;
  __syncthreads();
  for (int d = 1; d < 256; d <<= 1) {
    u32 v = (tid >= d) ? s[tid - d] : 0u;
    __syncthreads();
    s[tid] += v;
    __syncthreads();
  }
  const u32 off = s[tid] - pad;        // exclusive padded offset
  const u32 total = s[255];
  cur[tid] = off;
  for (u32 i = off + c; i < off + pad; i++) perm[i] = INVR;
  // u16 blk2b: bucket 255 is a REAL bucket, 0xFFFF is the dead sentinel
  for (u32 blk = off >> 6; blk < (off + pad) >> 6; blk++) blk2b[blk] = (u16)tid;
  for (u32 i = total + tid; i < PERM_TOT; i += 256) perm[i] = INVR;
  for (u32 blk = (total >> 6) + tid; blk < NBLK; blk += 256) blk2b[blk] = BLK_DEAD;
}

__global__ void k_scatter(const u8* __restrict__ bkt, u32* __restrict__ cur,
                          u32* __restrict__ perm) {
  __shared__ u32 h[256], base[256];
  const int tid = threadIdx.x;
  h[tid] = 0u;
  __syncthreads();
  const int r = blockIdx.x * 256 + tid;
  const u32 b = bkt[r];
  const u32 rank = atomicAdd(&h[b], 1u);
  __syncthreads();
  base[tid] = h[tid] ? atomicAdd(&cur[tid], h[tid]) : 0u;
  __syncthreads();
  perm[base[b] + rank] = (u32)r;
}

// ---------------- weight packing ----------------
// Tile (kt,nt): lane L holds B[kt*32 + (L>>4)*8 + j][nt*16 + (L&15)], j=0..7.
// Tile order [e][nt][kt].

struct PrepArgs {
  const float* src[11];
  int K[11], Nsrc[11];
  int tileStart[12];
};

__global__ void k_prep(__bf16* __restrict__ pk, PrepArgs pa) {
  const int tid = threadIdx.x;
  const int gt = blockIdx.x * 4 + (tid >> 6);
  const int lane = tid & 63, quad = lane >> 4, l16 = lane & 15;
  int m = 0;
  while (gt >= pa.tileStart[m + 1]) m++;
  const int loc = gt - pa.tileStart[m];
  const int K = pa.K[m], Ns = pa.Nsrc[m];
  const int Np = Ns < 16 ? 16 : Ns;
  const int KT = K >> 5, NT = Np >> 4;
  const int e = loc / (KT * NT), rem = loc % (KT * NT);
  const int nt = rem / KT, kt = rem % KT;
  const int k = kt * 32 + quad * 8, n = nt * 16 + l16;
  u32 hw[4];
  if (n < Ns) {
    const float* s = pa.src[m] + ((size_t)e * K + k) * Ns + n;
    u16 h[8];
#pragma unroll
    for (int j = 0; j < 8; j++) h[j] = f2bf(s[(size_t)j * Ns]);
    hw[0] = (u32)h[0] | ((u32)h[1] << 16);
    hw[1] = (u32)h[2] | ((u32)h[3] << 16);
    hw[2] = (u32)h[4] | ((u32)h[5] << 16);
    hw[3] = (u32)h[6] | ((u32)h[7] << 16);
  } else {
    hw[0] = hw[1] = hw[2] = hw[3] = 0u;
  }
  uint4 w; w.x = hw[0]; w.y = hw[1]; w.z = hw[2]; w.w = hw[3];
  *(uint4*)((char*)pk + (size_t)gt * 1024 + lane * 16) = w;
}

// ---------------- fused node-chain kernel ----------------

__device__ __forceinline__ void xj_load(const float* inp, u32 myrow, int tid, int node,
                                        float4& v0, float4& v1) {
  v0 = make_float4(0.f, 0.f, 0.f, 0.f); v1 = v0;
  if (myrow != INVR) {
    const int c8 = (tid & 3) << 3;
    const float4* p = (const float4*)(inp + (size_t)myrow * 144 + node * 32 + c8);
    v0 = p[0]; v1 = p[1];
  }
}

// XJ fragment store: row r = tid>>2 holds cols c8..c8+7 (c8 = (tid&3)*8) -> exactly
// one lane-slot of tile (r>>4): lane = (r&15) + 16*(tid&3).
__device__ __forceinline__ void xj_store(char* sm, int tid, float4 v0, float4 v1) {
  const int r = tid >> 2;
  uint4 w;
  w.x = (u32)f2bf(v0.x) | ((u32)f2bf(v0.y) << 16);
  w.y = (u32)f2bf(v0.z) | ((u32)f2bf(v0.w) << 16);
  w.z = (u32)f2bf(v1.x) | ((u32)f2bf(v1.y) << 16);
  w.w = (u32)f2bf(v1.z) | ((u32)f2bf(v1.w) << 16);
  *(uint4*)(sm + O_XJ + ((r >> 4) << 10) + ((((tid & 3) << 4) + (r & 15)) << 4)) = w;
}

// h = relu(xj @ Wp + bp) -> H  (also node0's first GEMM)
__device__ __forceinline__ void pre_gemm(char* sm, u32 e, int wave, int lane,
                                         const __bf16* Wp, const float* bp) {
  const int l16 = lane & 15;
  const int wn0 = wave * 64;
  const int rsel = ((lane >> 4) << 2) + ((l16 & 1) ? 2 : 0);
  const int colp = l16 & ~1;
  float bias[4];
#pragma unroll
  for (int nt = 0; nt < 4; nt++) bias[nt] = bp[(size_t)e * 256 + wn0 + nt * 16 + l16];
  f32x4 acc[4][4];
#pragma unroll
  for (int i = 0; i < 4; i++)
#pragma unroll
    for (int j = 0; j < 4; j++) acc[i][j] = (f32x4){0.f, 0.f, 0.f, 0.f};
  bf16x8 a[4], b[4];
#pragma unroll
  for (int nt = 0; nt < 4; nt++)
    b[nt] = *(const bf16x8*)(Wp + (size_t)(e * 16 + (wn0 >> 4) + nt) * 512 + lane * 8);
#pragma unroll
  for (int mt = 0; mt < 4; mt++)
    a[mt] = *(const bf16x8*)(sm + O_XJ + (mt << 10) + lane * 16);
#pragma unroll
  for (int mt = 0; mt < 4; mt++)
#pragma unroll
    for (int nt = 0; nt < 4; nt++) acc[mt][nt] = mfma16(a[mt], b[nt], acc[mt][nt]);
#pragma unroll
  for (int nt = 0; nt < 4; nt++) {
    const int n = wn0 + nt * 16;
#pragma unroll
    for (int mt = 0; mt < 4; mt++) {
      u32 w0, w1;
      mkpair(acc[mt][nt], bias[nt], true, l16, w0, w1);
      frag_store_pair(sm + O_H, 8, mt * 16 + rsel, n + colp, w0, w1);
    }
  }
}

// h = relu(cat(P, H) @ Wm + bm) -> H   (K=384; kt 0..3 from P, 4..11 from H)
__device__ __forceinline__ void main_gemm(char* sm, u32 e, int wave, int lane,
                                          const __bf16* Wm, const float* bm) {
  const int l16 = lane & 15;
  const int wn0 = wave * 64;
  const int rsel = ((lane >> 4) << 2) + ((l16 & 1) ? 2 : 0);
  const int colp = l16 & ~1;
  float bias[4];
#pragma unroll
  for (int nt = 0; nt < 4; nt++) bias[nt] = bm[(size_t)e * 256 + wn0 + nt * 16 + l16];
  f32x4 acc[4][4];
#pragma unroll
  for (int i = 0; i < 4; i++)
#pragma unroll
    for (int j = 0; j < 4; j++) acc[i][j] = (f32x4){0.f, 0.f, 0.f, 0.f};
  const __bf16* bB = Wm + (size_t)(e * 16 + (wn0 >> 4)) * 12 * 512 + lane * 8;
  bf16x8 bb[2][4];
#pragma unroll
  for (int nt = 0; nt < 4; nt++) {
    bb[0][nt] = *(const bf16x8*)(bB + (size_t)(nt * 12 + 0) * 512);
    bb[1][nt] = *(const bf16x8*)(bB + (size_t)(nt * 12 + 1) * 512);
  }
#pragma unroll
  for (int kt = 0; kt < 12; kt++) {
    bf16x8 a[4];
#pragma unroll
    for (int mt = 0; mt < 4; mt++) {
      a[mt] = (kt < 4)
          ? *(const bf16x8*)(sm + O_P + ((mt * 4 + kt) << 10) + lane * 16)
          : *(const bf16x8*)(sm + O_H + ((mt * 8 + (kt - 4)) << 10) + lane * 16);
    }
#pragma unroll
    for (int mt = 0; mt < 4; mt++)
#pragma unroll
      for (int nt = 0; nt < 4; nt++) acc[mt][nt] = mfma16(a[mt], bb[kt & 1][nt], acc[mt][nt]);
    if (kt < 10) {
#pragma unroll
      for (int nt = 0; nt < 4; nt++)
        bb[kt & 1][nt] = *(const bf16x8*)(bB + (size_t)(nt * 12 + kt + 2) * 512);
    }
  }
  __syncthreads();   // all waves done reading P/H before H is overwritten
#pragma unroll
  for (int nt = 0; nt < 4; nt++) {
    const int n = wn0 + nt * 16;
#pragma unroll
    for (int mt = 0; mt < 4; mt++) {
      u32 w0, w1;
      mkpair(acc[mt][nt], bias[nt], true, l16, w0, w1);
      frag_store_pair(sm + O_H, 8, mt * 16 + rsel, n + colp, w0, w1);
    }
  }
  __syncthreads();
}

// xnext = relu(H @ Wo + bo) -> P  (nodes 0..2)
__device__ __forceinline__ void out_gemm(char* sm, u32 e, int wave, int lane,
                                         const __bf16* Wo, const float* bo) {
  const int l16 = lane & 15;
  const int on0 = wave * 32;
  const int rsel = ((lane >> 4) << 2) + ((l16 & 1) ? 2 : 0);
  const int colp = l16 & ~1;
  float bias[2];
#pragma unroll
  for (int nt = 0; nt < 2; nt++) bias[nt] = bo[(size_t)e * 128 + on0 + nt * 16 + l16];
  f32x4 acc[4][2];
#pragma unroll
  for (int i = 0; i < 4; i++) { acc[i][0] = (f32x4){0.f,0.f,0.f,0.f}; acc[i][1] = acc[i][0]; }
  const __bf16* bB = Wo + (size_t)(e * 8 + (on0 >> 4)) * 8 * 512 + lane * 8;
  bf16x8 bb[2][2];
#pragma unroll
  for (int nt = 0; nt < 2; nt++) {
    bb[0][nt] = *(const bf16x8*)(bB + (size_t)(nt * 8 + 0) * 512);
    bb[1][nt] = *(const bf16x8*)(bB + (size_t)(nt * 8 + 1) * 512);
  }
#pragma unroll
  for (int kt = 0; kt < 8; kt++) {
    bf16x8 a[4];
#pragma unroll
    for (int mt = 0; mt < 4; mt++)
      a[mt] = *(const bf16x8*)(sm + O_H + ((mt * 8 + kt) << 10) + lane * 16);
#pragma unroll
    for (int mt = 0; mt < 4; mt++)
#pragma unroll
      for (int nt = 0; nt < 2; nt++) acc[mt][nt] = mfma16(a[mt], bb[kt & 1][nt], acc[mt][nt]);
    if (kt < 6) {
#pragma unroll
      for (int nt = 0; nt < 2; nt++)
        bb[kt & 1][nt] = *(const bf16x8*)(bB + (size_t)(nt * 8 + kt + 2) * 512);
    }
  }
#pragma unroll
  for (int nt = 0; nt < 2; nt++) {
    const int n = on0 + nt * 16;
#pragma unroll
    for (int mt = 0; mt < 4; mt++) {
      u32 w0, w1;
      mkpair(acc[mt][nt], bias[nt], true, l16, w0, w1);
      frag_store_pair(sm + O_P, 4, mt * 16 + rsel, n + colp, w0, w1);
    }
  }
}

__global__ __launch_bounds__(256, 3) void fused_k(
    const float* __restrict__ inp, const u32* __restrict__ perm,
    const u16* __restrict__ blk2b, const __bf16* __restrict__ pk,
    const float* __restrict__ b0_0, const float* __restrict__ b0_1,
    const float* __restrict__ b1_p, const float* __restrict__ b1_0,
    const float* __restrict__ b1_1, const float* __restrict__ b2_p,
    const float* __restrict__ b2_0, const float* __restrict__ b2_1,
    const float* __restrict__ b3_p, const float* __restrict__ b3_0,
    const float* __restrict__ b3_1, float* __restrict__ dout) {
  const u32 b = blk2b[blockIdx.x];
  if (b == BLK_DEAD) return;
  __shared__ __align__(16) char sm[SM_BYTES];
  u32* rows = (u32*)sm;
  const int tid = threadIdx.x;
  const int wave = tid >> 6, lane = tid & 63, quad = lane >> 4, l16 = lane & 15;
  if (tid < 64) rows[tid] = perm[blockIdx.x * 64 + tid];
  const u32 e0 = b & 3u, e1 = (b >> 2) & 3u, e2 = (b >> 4) & 3u, e3 = (b >> 6) & 3u;
  __syncthreads();
  const u32 myrow = rows[tid >> 2];

  float4 v0, v1;
  // ---- node 0 ----
  xj_load(inp, myrow, tid, 0, v0, v1);
  xj_store(sm, tid, v0, v1);
  __syncthreads();
  pre_gemm(sm, e0, wave, lane, pk + (size_t)TS(0) * 512, b0_0);   // h0 -> H
  __syncthreads();
  // ---- node 1 ----
  xj_load(inp, myrow, tid, 1, v0, v1);
  out_gemm(sm, e0, wave, lane, pk + (size_t)TS(1) * 512, b0_1);   // x -> P
  xj_store(sm, tid, v0, v1);
  __syncthreads();
  pre_gemm(sm, e1, wave, lane, pk + (size_t)TS(2) * 512, b1_p);
  __syncthreads();
  main_gemm(sm, e1, wave, lane, pk + (size_t)TS(3) * 512, b1_0);
  // ---- node 2 ----
  xj_load(inp, myrow, tid, 2, v0, v1);
  out_gemm(sm, e1, wave, lane, pk + (size_t)TS(4) * 512, b1_1);
  xj_store(sm, tid, v0, v1);
  __syncthreads();
  pre_gemm(sm, e2, wave, lane, pk + (size_t)TS(5) * 512, b2_p);
  __syncthreads();
  main_gemm(sm, e2, wave, lane, pk + (size_t)TS(6) * 512, b2_0);
  // ---- node 3 ----
  xj_load(inp, myrow, tid, 3, v0, v1);
  out_gemm(sm, e2, wave, lane, pk + (size_t)TS(7) * 512, b2_1);
  xj_store(sm, tid, v0, v1);
  __syncthreads();
  pre_gemm(sm, e3, wave, lane, pk + (size_t)TS(8) * 512, b3_p);
  __syncthreads();
  main_gemm(sm, e3, wave, lane, pk + (size_t)TS(9) * 512, b3_0);

  // out3: [64x256] @ W3_1[256x16pad] + b -> dout fp32 (K split across waves)
  {
    const __bf16* Wo3 = pk + (size_t)TS(10) * 512;
    f32x4 acc3[4];
#pragma unroll
    for (int i = 0; i < 4; i++) acc3[i] = (f32x4){0.f, 0.f, 0.f, 0.f};
#pragma unroll
    for (int kk = 0; kk < 2; kk++) {
      const int kt = wave * 2 + kk;
      bf16x8 b3 = *(const bf16x8*)(Wo3 + (size_t)(e3 * 8 + kt) * 512 + lane * 8);
      bf16x8 a[4];
#pragma unroll
      for (int mt = 0; mt < 4; mt++)
        a[mt] = *(const bf16x8*)(sm + O_H + ((mt * 8 + kt) << 10) + lane * 16);
#pragma unroll
      for (int mt = 0; mt < 4; mt++) acc3[mt] = mfma16(a[mt], b3, acc3[mt]);
    }
#pragma unroll
    for (int mt = 0; mt < 4; mt++)
#pragma unroll
      for (int r = 0; r < 4; r++)
        *(float*)(sm + O_RED +
                  (((size_t)wave * 64 + mt * 16 + quad * 4 + r) * 16 + l16) * 4) = acc3[mt][r];
    __syncthreads();
    const int m = tid >> 2, c = (tid & 3) * 2;
    float s0 = 0.f, s1 = 0.f;
#pragma unroll
    for (int w = 0; w < 4; w++) {
      s0 += *(float*)(sm + O_RED + (((size_t)w * 64 + m) * 16 + c) * 4);
      s1 += *(float*)(sm + O_RED + (((size_t)w * 64 + m) * 16 + c + 1) * 4);
    }
    if (myrow != INVR) {
      float2 o;
      o.x = s0 + b3_1[(size_t)e3 * 8 + c];
      o.y = s1 + b3_1[(size_t)e3 * 8 + c + 1];
      *(float2*)(dout + (size_t)myrow * 8 + c) = o;
    }
  }
}

// ---------------- host ----------------

extern "C" void kernel_launch(void* const* d_in, const int* in_sizes, int n_in,
                              void* d_out, int out_size, void* d_ws, size_t ws_size,
                              hipStream_t stream) {
  (void)in_sizes; (void)n_in; (void)out_size; (void)ws_size;
  const float* inp = (const float*)d_in[0];
  char* ws = (char*)d_ws;

  const size_t oCNT = 0;                       // 256 u32
  const size_t oCUR = 1024;                    // 256 u32
  const size_t oBKT = 2048;                    // NB u8
  const size_t oB2B = oBKT + NB;               // NBLK u16
  const size_t oPERM = (oB2B + NBLK * 2 + 255) & ~(size_t)255;
  const size_t oPK = (oPERM + (size_t)PERM_TOT * 4 + 255) & ~(size_t)255;

  u32* cnt = (u32*)(ws + oCNT);
  u32* cur = (u32*)(ws + oCUR);
  u8* bkt = (u8*)(ws + oBKT);
  u16* blk2b = (u16*)(ws + oB2B);
  u32* perm = (u32*)(ws + oPERM);
  __bf16* pk = (__bf16*)(ws + oPK);

  PrepArgs pa;
  const int widx[11] = {1, 3, 5, 7, 9, 11, 13, 15, 17, 19, 21};
  const int Ks[11] = {32, 256, 32, 384, 256, 32, 384, 256, 32, 384, 256};
  const int Ns[11] = {256, 128, 256, 256, 128, 256, 256, 128, 256, 256, 8};
  for (int m = 0; m < 11; m++) {
    pa.src[m] = (const float*)d_in[widx[m]];
    pa.K[m] = Ks[m]; pa.Nsrc[m] = Ns[m]; pa.tileStart[m] = TS(m);
  }
  pa.tileStart[11] = TS(11);   // 3360 tiles

  hipLaunchKernelGGL(k_init, dim3(1), dim3(256), 0, stream, cnt);
  hipLaunchKernelGGL(k_prep, dim3(TS(11) / 4), dim3(256), 0, stream, pk, pa);
  hipLaunchKernelGGL(k_route, dim3(NB / 256), dim3(256), 0, stream, inp, bkt, cnt);
  hipLaunchKernelGGL(k_scan, dim3(1), dim3(256), 0, stream, cnt, cur, blk2b, perm);
  hipLaunchKernelGGL(k_scatter, dim3(NB / 256), dim3(256), 0, stream, bkt, cur, perm);

  fused_k<<<NBLK, 256, 0, stream>>>(
      inp, perm, blk2b, pk,
      (const float*)d_in[2], (const float*)d_in[4],
      (const float*)d_in[6], (const float*)d_in[8], (const float*)d_in[10],
      (const float*)d_in[12], (const float*)d_in[14], (const float*)d_in[16],
      (const float*)d_in[18], (const float*)d_in[20], (const float*)d_in[22],
      (float*)d_out);
}